// Round 9
// baseline (23.433 us; speedup 1.0000x reference)
//
#include <hip/hip_runtime.h>

// loss = sum_{b,j} ||kps[b,j,:]||_2 * (norm > 1.0) / (B*J)
// Input: [524288, 17, 3] fp32 = 26,738,688 floats. Output: 1 fp32 scalar.
//
// R9 = R4 exactly, with ONE change: plain cacheable loads instead of
// __builtin_nontemporal_load. Theory: the 107 MB input fits in the 256 MB
// L3; graph replays re-read the same buffer, so cacheable loads let timed
// replays serve from Infinity Cache (> HBM BW). NT = no-allocate fights it.
//
// Kernel 1: grid-stride over 3072-float chunks, double-buffered LDS, one
// barrier per chunk, next chunk's wave-dense float4 loads issued pre-barrier.
// Kernel 2: single block reduces 2048 partials -> d_out.
// NO hipMemsetAsync in the graph (in-graph tiny fill costs ~22 us, R7).

#define GRID1 2048
#define BLOCK 256
#define CF4   768   // float4s per chunk = 3072 floats = 256 threads * 12 floats

typedef float vf4 __attribute__((ext_vector_type(4)));

__global__ __launch_bounds__(BLOCK) void body_loss_partial(
    const vf4* __restrict__ p4, float* __restrict__ partial, int nchunks) {
    __shared__ vf4 lds[2][CF4];
    const int t = threadIdx.x;
    float acc = 0.0f;

    int c = blockIdx.x;               // always < nchunks (8704 > 2048)
    {
        const vf4* g = p4 + (size_t)c * CF4;
        vf4 r0 = g[t];
        vf4 r1 = g[256 + t];
        vf4 r2 = g[512 + t];
        int cur = 0;
        lds[0][t] = r0; lds[0][256 + t] = r1; lds[0][512 + t] = r2;

        int next = c + GRID1;
        while (true) {
            const bool have_next = next < nchunks;
            if (have_next) {
                const vf4* gn = p4 + (size_t)next * CF4;
                r0 = gn[t];
                r1 = gn[256 + t];
                r2 = gn[512 + t];
            }
            __syncthreads();   // lds[cur] writes (end of prev iter) visible
            const vf4 v0 = lds[cur][3 * t + 0];
            const vf4 v1 = lds[cur][3 * t + 1];
            const vf4 v2 = lds[cur][3 * t + 2];
            const float d0 = sqrtf(v0.x * v0.x + v0.y * v0.y + v0.z * v0.z);
            const float d1 = sqrtf(v0.w * v0.w + v1.x * v1.x + v1.y * v1.y);
            const float d2 = sqrtf(v1.z * v1.z + v1.w * v1.w + v2.x * v2.x);
            const float d3 = sqrtf(v2.y * v2.y + v2.z * v2.z + v2.w * v2.w);
            acc += (d0 > 1.0f ? d0 : 0.0f);
            acc += (d1 > 1.0f ? d1 : 0.0f);
            acc += (d2 > 1.0f ? d2 : 0.0f);
            acc += (d3 > 1.0f ? d3 : 0.0f);
            if (!have_next) break;
            // lds[cur^1]'s readers finished before this iteration's barrier.
            cur ^= 1;
            lds[cur][t] = r0; lds[cur][256 + t] = r1; lds[cur][512 + t] = r2;
            next += GRID1;
        }
    }

    // 64-lane butterfly reduce, then combine 4 waves.
    #pragma unroll
    for (int off = 32; off > 0; off >>= 1)
        acc += __shfl_down(acc, off, 64);

    __shared__ float wsum[4];
    const int lane = t & 63, wid = t >> 6;
    if (lane == 0) wsum[wid] = acc;
    __syncthreads();
    if (t == 0)
        partial[blockIdx.x] = wsum[0] + wsum[1] + wsum[2] + wsum[3];
}

__global__ __launch_bounds__(BLOCK) void body_loss_final(
    const float* __restrict__ partial, float* __restrict__ out, float inv_norm) {
    const int t = threadIdx.x;
    // 2048 partials = 256 threads * 2 float4s.
    const vf4* p = (const vf4*)partial;
    const vf4 a = p[t];
    const vf4 b = p[256 + t];
    float s = a.x + a.y + a.z + a.w + b.x + b.y + b.z + b.w;
    #pragma unroll
    for (int off = 32; off > 0; off >>= 1)
        s += __shfl_down(s, off, 64);
    __shared__ float wsum[4];
    const int lane = t & 63, wid = t >> 6;
    if (lane == 0) wsum[wid] = s;
    __syncthreads();
    if (t == 0)
        out[0] = (wsum[0] + wsum[1] + wsum[2] + wsum[3]) * inv_norm;
}

extern "C" void kernel_launch(void* const* d_in, const int* in_sizes, int n_in,
                              void* d_out, int out_size, void* d_ws, size_t ws_size,
                              hipStream_t stream) {
    const float* in = (const float*)d_in[0];
    float* out = (float*)d_out;
    float* partial = (float*)d_ws;   // 2048 floats = 8 KB scratch

    const long long nfloats  = in_sizes[0];               // 26,738,688
    const long long ntriples = nfloats / 3;               // 8,912,896
    const int nchunks = (int)(nfloats / (CF4 * 4));       // 8704 exact
    const float inv_norm = 1.0f / (float)ntriples;

    body_loss_partial<<<GRID1, BLOCK, 0, stream>>>(
        (const vf4*)in, partial, nchunks);
    body_loss_final<<<1, BLOCK, 0, stream>>>(partial, out, inv_norm);
}

// Round 10
// 21.186 us; speedup vs baseline: 1.1060x; 1.1060x over previous
//
#include <hip/hip_runtime.h>

// loss = sum_{b,j} ||kps[b,j,:]||_2 * (norm > 1.0) / (B*J)
// Input: [524288, 17, 3] fp32 = 26,738,688 floats. Output: 1 fp32 scalar.
//
// FINAL (= R4, best measured: 21.0 us): grid-stride over 3072-float chunks,
// double-buffered LDS, one barrier per chunk, next chunk's wave-dense float4
// NT loads issued pre-barrier. Trailing 1-block kernel reduces 2048 partials.
//
// Locked-in lessons (A/B-measured this session):
//  - NT loads > cacheable here: harness fills ~427MB between replays, L3
//    never holds the input (R9: +2.4us without NT).
//  - NO hipMemsetAsync in the captured graph (R7: +22us for a 4-byte fill).
//  - NO __threadfence last-block fusion (R5: +82us, per-block L2 wb/inv).
//  - Deeper prefetch / wave-private staging don't help (R8 +1.2, R6 +2.6):
//    main loop sits at ~5.9 TB/s = 94% of the 6.29 TB/s copy ubench ceiling.

#define GRID1 2048
#define BLOCK 256
#define CF4   768   // float4s per chunk = 3072 floats = 256 threads * 12 floats

typedef float vf4 __attribute__((ext_vector_type(4)));

__global__ __launch_bounds__(BLOCK) void body_loss_partial(
    const vf4* __restrict__ p4, float* __restrict__ partial, int nchunks) {
    __shared__ vf4 lds[2][CF4];
    const int t = threadIdx.x;
    float acc = 0.0f;

    int c = blockIdx.x;               // always < nchunks (8704 > 2048)
    {
        const vf4* g = p4 + (size_t)c * CF4;
        vf4 r0 = __builtin_nontemporal_load(&g[t]);
        vf4 r1 = __builtin_nontemporal_load(&g[256 + t]);
        vf4 r2 = __builtin_nontemporal_load(&g[512 + t]);
        int cur = 0;
        lds[0][t] = r0; lds[0][256 + t] = r1; lds[0][512 + t] = r2;

        int next = c + GRID1;
        while (true) {
            const bool have_next = next < nchunks;
            if (have_next) {
                const vf4* gn = p4 + (size_t)next * CF4;
                r0 = __builtin_nontemporal_load(&gn[t]);
                r1 = __builtin_nontemporal_load(&gn[256 + t]);
                r2 = __builtin_nontemporal_load(&gn[512 + t]);
            }
            __syncthreads();   // lds[cur] writes (end of prev iter) visible
            const vf4 v0 = lds[cur][3 * t + 0];
            const vf4 v1 = lds[cur][3 * t + 1];
            const vf4 v2 = lds[cur][3 * t + 2];
            const float d0 = sqrtf(v0.x * v0.x + v0.y * v0.y + v0.z * v0.z);
            const float d1 = sqrtf(v0.w * v0.w + v1.x * v1.x + v1.y * v1.y);
            const float d2 = sqrtf(v1.z * v1.z + v1.w * v1.w + v2.x * v2.x);
            const float d3 = sqrtf(v2.y * v2.y + v2.z * v2.z + v2.w * v2.w);
            acc += (d0 > 1.0f ? d0 : 0.0f);
            acc += (d1 > 1.0f ? d1 : 0.0f);
            acc += (d2 > 1.0f ? d2 : 0.0f);
            acc += (d3 > 1.0f ? d3 : 0.0f);
            if (!have_next) break;
            // lds[cur^1]'s readers finished before this iteration's barrier.
            cur ^= 1;
            lds[cur][t] = r0; lds[cur][256 + t] = r1; lds[cur][512 + t] = r2;
            next += GRID1;
        }
    }

    // 64-lane butterfly reduce, then combine 4 waves.
    #pragma unroll
    for (int off = 32; off > 0; off >>= 1)
        acc += __shfl_down(acc, off, 64);

    __shared__ float wsum[4];
    const int lane = t & 63, wid = t >> 6;
    if (lane == 0) wsum[wid] = acc;
    __syncthreads();
    if (t == 0)
        partial[blockIdx.x] = wsum[0] + wsum[1] + wsum[2] + wsum[3];
}

__global__ __launch_bounds__(BLOCK) void body_loss_final(
    const float* __restrict__ partial, float* __restrict__ out, float inv_norm) {
    const int t = threadIdx.x;
    // 2048 partials = 256 threads * 2 float4s.
    const vf4* p = (const vf4*)partial;
    const vf4 a = p[t];
    const vf4 b = p[256 + t];
    float s = a.x + a.y + a.z + a.w + b.x + b.y + b.z + b.w;
    #pragma unroll
    for (int off = 32; off > 0; off >>= 1)
        s += __shfl_down(s, off, 64);
    __shared__ float wsum[4];
    const int lane = t & 63, wid = t >> 6;
    if (lane == 0) wsum[wid] = s;
    __syncthreads();
    if (t == 0)
        out[0] = (wsum[0] + wsum[1] + wsum[2] + wsum[3]) * inv_norm;
}

extern "C" void kernel_launch(void* const* d_in, const int* in_sizes, int n_in,
                              void* d_out, int out_size, void* d_ws, size_t ws_size,
                              hipStream_t stream) {
    const float* in = (const float*)d_in[0];
    float* out = (float*)d_out;
    float* partial = (float*)d_ws;   // 2048 floats = 8 KB scratch

    const long long nfloats  = in_sizes[0];               // 26,738,688
    const long long ntriples = nfloats / 3;               // 8,912,896
    const int nchunks = (int)(nfloats / (CF4 * 4));       // 8704 exact
    const float inv_norm = 1.0f / (float)ntriples;

    body_loss_partial<<<GRID1, BLOCK, 0, stream>>>(
        (const vf4*)in, partial, nchunks);
    body_loss_final<<<1, BLOCK, 0, stream>>>(partial, out, inv_norm);
}